// Round 7
// baseline (8340.350 us; speedup 1.0000x reference)
//
#include <hip/hip_runtime.h>
#include <stdint.h>

typedef _Float16 f16;
typedef _Float16 f16x8 __attribute__((ext_vector_type(8)));
typedef float f32x4 __attribute__((ext_vector_type(4)));

#define NBATCH 64

__device__ __forceinline__ float sigmoidf_(float x) {
    return 1.0f / (1.0f + __expf(-x));
}
__device__ __forceinline__ float tanh_(float x) {
    x = fminf(fmaxf(x, -15.0f), 15.0f);
    float e = __expf(2.0f * x);
    return (e - 1.0f) / (e + 1.0f);
}

// ---------------- fold LoRA into dense weight: dst = fp16(W + 2*B@A) --------
__global__ __launch_bounds__(256) void fold_lora(
    const float* __restrict__ W, const float* __restrict__ Bm,
    const float* __restrict__ Am, f16* __restrict__ dst, int K) {
    int cid = blockIdx.x * 256 + threadIdx.x;
    int kc = K >> 3;
    int r = cid / kc;
    int k0 = (cid - r * kc) * 8;
    float bb[8];
#pragma unroll
    for (int j = 0; j < 8; j++) bb[j] = Bm[r * 8 + j];
#pragma unroll
    for (int i = 0; i < 8; i++) {
        float s = 0.0f;
#pragma unroll
        for (int j = 0; j < 8; j++) s += bb[j] * Am[j * K + k0 + i];
        float v = W[(size_t)r * K + k0 + i] + 2.0f * s;
        dst[(size_t)r * K + k0 + i] = (f16)v;
    }
}

// ---------------- bias sums + flag/cstate zeroing ----------------------------
__global__ __launch_bounds__(256) void init_misc(
    const float* __restrict__ bih0, const float* __restrict__ bhh0,
    const float* __restrict__ bih1, const float* __restrict__ bhh1,
    float* __restrict__ bsum0, float* __restrict__ bsum1,
    int* __restrict__ flags0, int* __restrict__ flags1,
    float* __restrict__ c0, float* __restrict__ c1) {
    int i = blockIdx.x * 256 + threadIdx.x;
    if (i < 4096) {
        bsum0[i] = bih0[i] + bhh0[i];
        bsum1[i] = bih1[i] + bhh1[i];
    }
    if (i < 256) { flags0[i] = 0; flags1[i] = 0; }
    c0[i] = 0.0f;
    c1[i] = 0.0f;
}

// ---------------- embedding gather chunk -> fp16 seqc [CH][B][512] -----------
__global__ __launch_bounds__(256) void embed_gather(
    const int* __restrict__ x, const float* __restrict__ emb,
    f16* __restrict__ seqc, int t0) {
    int lt = blockIdx.x;
    int t = t0 + lt;
#pragma unroll
    for (int c = 0; c < 16; c++) {
        int lin = c * 256 + threadIdx.x;
        int b = lin >> 6;
        int e0 = (lin & 63) * 8;
        int tok = x[b * 512 + t];
        const float* src = emb + (size_t)tok * 512 + e0;
        f16x8 v;
#pragma unroll
        for (int i = 0; i < 8; i++) v[i] = (f16)src[i];
        *(f16x8*)&seqc[((size_t)lt * 64 + b) * 512 + e0] = v;
    }
}

// ---------------- 128x128 GEMM tile body (shared by standalone + in-dual) ----
// C = A[128 rows of M][K] @ Bw[128 rows of N][K]^T, gate-interleaved C write.
// ATOMIC_A: stage A via agent-scope uint64 loads (device-coherent; used for
// same-dispatch reads of h published by chain A with agent-scope stores).
template <bool ATOMIC_A>
__device__ __forceinline__ void gemm_tile(
    f16* As, f16* Bs, const f16* Aplain, const uint64_t* A64,
    const f16* __restrict__ Bw, float* __restrict__ C,
    int K, int mt, int nt) {
    int tid = threadIdx.x;
    int w = tid >> 6, lane = tid & 63;
    int lm = lane & 15, lq = lane >> 4;
    int wm = (w >> 1) * 64, wn = (w & 1) * 64;
    f32x4 acc[4][4];
#pragma unroll
    for (int i = 0; i < 4; i++)
#pragma unroll
        for (int j = 0; j < 4; j++) acc[i][j] = f32x4{0.f, 0.f, 0.f, 0.f};
    const f16* Ab = Aplain + (size_t)mt * 128 * K;
    const uint64_t* Ab64 = A64 + (size_t)mt * 128 * (K >> 2);
    const f16* Bb = Bw + (size_t)nt * 128 * K;
    int nkc = K >> 5;
    for (int kc = 0; kc < nkc; kc++) {
#pragma unroll
        for (int i = 0; i < 2; i++) {
            int cid = tid + i * 256;
            int r = cid >> 2, c8 = (cid & 3) * 8;
            if (ATOMIC_A) {
                size_t o = (size_t)r * (K >> 2) + (size_t)kc * 8 + (c8 >> 2);
                uint64_t v0 = __hip_atomic_load(Ab64 + o, __ATOMIC_RELAXED,
                                                __HIP_MEMORY_SCOPE_AGENT);
                uint64_t v1 = __hip_atomic_load(Ab64 + o + 1, __ATOMIC_RELAXED,
                                                __HIP_MEMORY_SCOPE_AGENT);
                *(uint64_t*)&As[r * 40 + c8] = v0;
                *(uint64_t*)&As[r * 40 + c8 + 4] = v1;
            } else {
                *(f16x8*)&As[r * 40 + c8] =
                    *(const f16x8*)&Ab[(size_t)r * K + kc * 32 + c8];
            }
            *(f16x8*)&Bs[r * 40 + c8] =
                *(const f16x8*)&Bb[(size_t)r * K + kc * 32 + c8];
        }
        __syncthreads();
        f16x8 af[4], bf[4];
#pragma unroll
        for (int mi = 0; mi < 4; mi++)
            af[mi] = *(const f16x8*)&As[(wm + mi * 16 + lm) * 40 + lq * 8];
#pragma unroll
        for (int ni = 0; ni < 4; ni++)
            bf[ni] = *(const f16x8*)&Bs[(wn + ni * 16 + lm) * 40 + lq * 8];
#pragma unroll
        for (int mi = 0; mi < 4; mi++)
#pragma unroll
            for (int ni = 0; ni < 4; ni++)
                acc[mi][ni] = __builtin_amdgcn_mfma_f32_16x16x32_f16(
                    af[mi], bf[ni], acc[mi][ni], 0, 0, 0);
        __syncthreads();
    }
#pragma unroll
    for (int mi = 0; mi < 4; mi++)
#pragma unroll
        for (int ni = 0; ni < 4; ni++)
#pragma unroll
            for (int r = 0; r < 4; r++) {
                int m = mt * 128 + wm + mi * 16 + lq * 4 + r;
                int n = nt * 128 + wn + ni * 16 + lm;
                int gate = n >> 10, u = n & 1023;
                C[(size_t)m * 4096 + u * 4 + gate] = acc[mi][ni][r];
            }
}

// ---------------- standalone NT GEMM (prologue chunk-0 xp only) --------------
__global__ __launch_bounds__(256) void gemm_nt(
    const f16* __restrict__ A, const f16* __restrict__ Bw,
    float* __restrict__ C, int K, int mtmask, int mtshift) {
    __shared__ __align__(16) char smem[20480];
    int bid = blockIdx.x;
    gemm_tile<false>((f16*)smem, (f16*)(smem + 10240), A, nullptr, Bw, C, K,
                     bid & mtmask, bid >> mtshift);
}

// ---------------- dual-chain persistent recurrence + streamed GEMMs ----------
// Blocks 0..255: layer-0 chunk c. Blocks 256..511: layer-1 chunk c-1.
// Blocks 512..767: gemm partition -- gemm0(c+1) (no deps: seqc from a prior
// embed dispatch, xp0 double-buffered) then gemm1(c) STREAMING against chain
// A's monotone flags (tile mt needs timesteps 2mt,2mt+1 -> poll all 256
// flags0 >= t0a+2mt+2), reading h0c via the same agent-scope loads stage_h
// uses. Wait graph acyclic: gemm waits on chain A only; chains never wait on
// gemm (their xp comes from the previous dispatch). 3 blocks/CU (LDS 3*37376
// <= 160K, launch_bounds(256,3) caps VGPR at 170).

__device__ __forceinline__ void stage_h(f16* hbuf, const uint32_t* hx, int slot,
                                        int bg, int tid) {
    const uint64_t* hp = (const uint64_t*)hx + (size_t)slot * (NBATCH * 256);
#pragma unroll
    for (int i = 0; i < 16; i++) {
        int lin = tid + i * 256;          // [0,4096) 8B granules
        int b = lin >> 8, d = lin & 255;
        uint64_t v = __hip_atomic_load(hp + (size_t)(bg * 16 + b) * 256 + d,
                                       __ATOMIC_RELAXED, __HIP_MEMORY_SCOPE_AGENT);
        *(uint64_t*)((char*)hbuf + (size_t)b * 2064 + (size_t)d * 8) = v;
    }
}

__device__ __forceinline__ f32x4 recur_mfma(const f16* hb, const f16x8* wf) {
    f32x4 a0 = f32x4{0.f, 0.f, 0.f, 0.f};
    f32x4 a1 = f32x4{0.f, 0.f, 0.f, 0.f};
    f32x4 a2 = f32x4{0.f, 0.f, 0.f, 0.f};
    f32x4 a3 = f32x4{0.f, 0.f, 0.f, 0.f};
#pragma unroll
    for (int kk = 0; kk < 32; kk += 4) {
        a0 = __builtin_amdgcn_mfma_f32_16x16x32_f16(*(const f16x8*)(hb + (kk + 0) * 32), wf[kk + 0], a0, 0, 0, 0);
        a1 = __builtin_amdgcn_mfma_f32_16x16x32_f16(*(const f16x8*)(hb + (kk + 1) * 32), wf[kk + 1], a1, 0, 0, 0);
        a2 = __builtin_amdgcn_mfma_f32_16x16x32_f16(*(const f16x8*)(hb + (kk + 2) * 32), wf[kk + 2], a2, 0, 0, 0);
        a3 = __builtin_amdgcn_mfma_f32_16x16x32_f16(*(const f16x8*)(hb + (kk + 3) * 32), wf[kk + 3], a3, 0, 0, 0);
    }
    return (a0 + a1) + (a2 + a3);
}

// verified single-layer recurrence loop, parameterized by logical bid
__device__ __forceinline__ void chain_loop(
    const float* __restrict__ xp, const f16* __restrict__ Wh,
    const float* __restrict__ bsum, uint32_t* __restrict__ hexch,
    int* __restrict__ flags, float* __restrict__ cstate,
    int t0, int smask, const int* __restrict__ lengths,
    float* __restrict__ dout, int bid, int nsteps,
    f16* hbuf, float* xch) {
    int tid = threadIdx.x;
    int g = tid >> 6, lane = tid & 63;
    int lm = lane & 15, lq = lane >> 4;
    int bg = bid >> 6, jg = bid & 63;

    // W fragments resident in registers for all steps
    f16x8 wfrag[32];
    {
        int grow = g * 1024 + jg * 16 + lm;
        const f16* wp = Wh + (size_t)grow * 1024 + lq * 8;
#pragma unroll
        for (int kk = 0; kk < 32; kk++) wfrag[kk] = *(const f16x8*)(wp + kk * 32);
    }
    int eb = tid >> 4, eu = tid & 15;
    int batch = bg * 16 + eb;
    int hidx = jg * 16 + eu;
    float bias[4];
#pragma unroll
    for (int g2 = 0; g2 < 4; g2++) bias[g2] = bsum[g2 * 1024 + hidx];
    int mylen = (lengths != nullptr) ? lengths[batch] : -1;
    float c = (t0 > 0) ? cstate[(size_t)batch * 1024 + hidx] : 0.0f;
    const int myflag = bg * 64 + jg;

    for (int lt = 0; lt < nsteps; lt++) {
        int t = t0 + lt;
        // prefetch xp (recurrence-independent): latency hides under flag wait
        const f32x4 xpv = *(const f32x4*)(xp + ((size_t)lt * 64 + batch) * 4096 + (hidx << 2));
        f32x4 pre = f32x4{0.f, 0.f, 0.f, 0.f};
        if (t > 0) {
            if (tid < 64) {
                const int* fl = flags + bg * 64;
                for (;;) {
                    int v = __hip_atomic_load(fl + tid, __ATOMIC_RELAXED,
                                              __HIP_MEMORY_SCOPE_AGENT);
                    if (__all(v >= t)) break;
                    __builtin_amdgcn_s_sleep(1);
                }
            }
            __syncthreads();
            stage_h(hbuf, hexch, (t - 1) & smask, bg, tid);
            __syncthreads();
            pre = recur_mfma(&hbuf[lm * 1032 + lq * 8], wfrag);
        }
        // cross-wave exchange: D element (m=lq*4+r = batch-in-group, n=lm)
#pragma unroll
        for (int r = 0; r < 4; r++)
            xch[(g * 16 + lq * 4 + r) * 16 + lm] = pre[r];
        __syncthreads();
        float pg[4];
#pragma unroll
        for (int g2 = 0; g2 < 4; g2++)
            pg[g2] = xch[(g2 * 16 + eb) * 16 + eu] + xpv[g2] + bias[g2];
        float iv = sigmoidf_(pg[0]);
        float fv = sigmoidf_(pg[1]);
        float gv = tanh_(pg[2]);
        float ov = sigmoidf_(pg[3]);
        c = fv * c + iv * gv;
        float h = ov * tanh_(c);
        float hn = __shfl_xor(h, 1);
        if ((tid & 1) == 0) {
            uint16_t lo, hi;
            {
                f16 a = (f16)h, b2 = (f16)hn;
                lo = *(uint16_t*)&a; hi = *(uint16_t*)&b2;
            }
            uint32_t pk = (uint32_t)lo | ((uint32_t)hi << 16);
            __hip_atomic_store(
                hexch + (size_t)(t & smask) * (NBATCH * 512)
                      + (size_t)batch * 512 + (hidx >> 1),
                pk, __ATOMIC_RELAXED, __HIP_MEMORY_SCOPE_AGENT);
        }
        if (dout != nullptr && t == mylen - 1)
            dout[(size_t)batch * 1024 + hidx] = h;
        __syncthreads();  // drains vmcnt(0): all waves' h stores are at the MALL
        if (tid == 0)
            __hip_atomic_store(flags + myflag, t + 1, __ATOMIC_RELAXED,
                               __HIP_MEMORY_SCOPE_AGENT);
    }
    cstate[(size_t)batch * 1024 + hidx] = c;
}

__global__ __launch_bounds__(256, 3) void lstm_dual(
    const float* __restrict__ xpA, const f16* __restrict__ WhA,
    const float* __restrict__ bsA, uint32_t* __restrict__ hxA,
    int* __restrict__ flagsA, float* __restrict__ cstA, int t0a, int smaskA,
    const float* __restrict__ xpB, const f16* __restrict__ WhB,
    const float* __restrict__ bsB, uint32_t* __restrict__ hxB,
    int* __restrict__ flagsB, float* __restrict__ cstB, int t0b,
    const int* __restrict__ lengths, float* __restrict__ dout, int nsteps,
    const f16* __restrict__ seqcN, const f16* __restrict__ W0f,
    const f16* __restrict__ W1f, float* __restrict__ xp0out,
    float* __restrict__ xp1out, int tpb, int mtmaskG, int mtshiftG) {
    __shared__ __align__(16) char smem[37376];
    const int cid = blockIdx.x;
    if (cid < 256) {
        if (t0a < 0) return;           // uniform per block, before any barrier
        chain_loop(xpA, WhA, bsA, hxA, flagsA, cstA, t0a, smaskA,
                   nullptr, nullptr, cid, nsteps,
                   (f16*)smem, (float*)(smem + 33024));
    } else if (cid < 512) {
        if (t0b < 0) return;
        chain_loop(xpB, WhB, bsB, hxB, flagsB, cstB, t0b, 1,
                   lengths, dout, cid - 256, nsteps,
                   (f16*)smem, (float*)(smem + 33024));
    } else {
        f16* As = (f16*)smem;
        f16* Bs = (f16*)(smem + 10240);
        const int gb = cid - 512;
        // gemm0(c+1): no intra-dispatch deps; fills the chains' idle shadow
        if (seqcN != nullptr) {
            for (int j = 0; j < tpb; j++) {
                int id = gb * tpb + j;
                gemm_tile<false>(As, Bs, seqcN, nullptr, W0f, xp0out, 512,
                                 id & mtmaskG, id >> mtshiftG);
            }
        }
        // gemm1(c): stream against chain A's flags
        if (t0a >= 0) {
            for (int j = 0; j < tpb; j++) {
                int id = gb * tpb + j;
                int mt = id & mtmaskG, nt = id >> mtshiftG;
                int tneed = t0a + 2 * mt + 2;
                if (threadIdx.x < 64) {
                    int tx = threadIdx.x;
                    for (;;) {
                        int v0 = __hip_atomic_load(flagsA + tx, __ATOMIC_RELAXED,
                                                   __HIP_MEMORY_SCOPE_AGENT);
                        int v1 = __hip_atomic_load(flagsA + 64 + tx, __ATOMIC_RELAXED,
                                                   __HIP_MEMORY_SCOPE_AGENT);
                        int v2 = __hip_atomic_load(flagsA + 128 + tx, __ATOMIC_RELAXED,
                                                   __HIP_MEMORY_SCOPE_AGENT);
                        int v3 = __hip_atomic_load(flagsA + 192 + tx, __ATOMIC_RELAXED,
                                                   __HIP_MEMORY_SCOPE_AGENT);
                        int mn = min(min(v0, v1), min(v2, v3));
                        if (__all(mn >= tneed)) break;
                        __builtin_amdgcn_s_sleep(2);
                    }
                }
                __syncthreads();
                gemm_tile<true>(As, Bs, nullptr, (const uint64_t*)hxA, W1f,
                                xp1out, 1024, mt, nt);
            }
        }
    }
}

extern "C" void kernel_launch(void* const* d_in, const int* in_sizes, int n_in,
                              void* d_out, int out_size, void* d_ws, size_t ws_size,
                              hipStream_t stream) {
    const int*   x     = (const int*)d_in[0];
    const int*   len   = (const int*)d_in[1];
    const float* emb   = (const float*)d_in[2];
    const float* W_ih0 = (const float*)d_in[3];
    const float* b_ih0 = (const float*)d_in[4];
    const float* A_ih0 = (const float*)d_in[5];
    const float* B_ih0 = (const float*)d_in[6];
    const float* W_hh0 = (const float*)d_in[7];
    const float* b_hh0 = (const float*)d_in[8];
    const float* A_hh0 = (const float*)d_in[9];
    const float* B_hh0 = (const float*)d_in[10];
    const float* W_ih1 = (const float*)d_in[11];
    const float* b_ih1 = (const float*)d_in[12];
    const float* A_ih1 = (const float*)d_in[13];
    const float* B_ih1 = (const float*)d_in[14];
    const float* W_hh1 = (const float*)d_in[15];
    const float* b_hh1 = (const float*)d_in[16];
    const float* A_hh1 = (const float*)d_in[17];
    const float* B_hh1 = (const float*)d_in[18];

    char* ws = (char*)d_ws;
    size_t off = 0;
    auto alloc = [&](size_t bytes) {
        size_t o = off;
        off += (bytes + 255) & ~(size_t)255;
        return o;
    };
    f16*   W0f    = (f16*)(ws + alloc((size_t)4096 * 512 * 2));
    f16*   Wh0f   = (f16*)(ws + alloc((size_t)4096 * 1024 * 2));
    f16*   W1f    = (f16*)(ws + alloc((size_t)4096 * 1024 * 2));
    f16*   Wh1f   = (f16*)(ws + alloc((size_t)4096 * 1024 * 2));
    float* bsum0  = (float*)(ws + alloc(4096 * 4));
    float* bsum1  = (float*)(ws + alloc(4096 * 4));
    int*   flags0 = (int*)(ws + alloc(4096));
    int*   flags1 = (int*)(ws + alloc(4096));
    float* c0st   = (float*)(ws + alloc((size_t)64 * 1024 * 4));
    float* c1st   = (float*)(ws + alloc((size_t)64 * 1024 * 4));
    f16*   hx1    = (f16*)(ws + alloc((size_t)2 * 64 * 1024 * 2));

    // chunk length: prefer 64, fall back to 32 if double-buffered xp0/xp1 +
    // double seqc don't fit. (Round-6 ran with ~184 MB -> the 32 rung, which
    // needs ~165 MB, always fits.)
    auto al = [](size_t b) { return (b + 255) & ~(size_t)255; };
    auto need_for = [&](size_t CH) {
        return off + 2 * al(CH * 64 * 512 * 2)        // seqc x2
                   + al(CH * 64 * 1024 * 2)           // h0 ring
                   + 4 * al(CH * 64 * 4096 * 4);      // xp0 x2 + xp1 x2
    };
    int CHv = (ws_size >= need_for(64)) ? 64 : 32;
    const int NCHv = 512 / CHv;
    const size_t seqcE = (size_t)CHv * 64 * 512;      // f16 elems per buffer
    const size_t xpE   = (size_t)CHv * 64 * 4096;     // f32 elems per buffer
    f16*   seqc = (f16*)(ws + alloc(2 * al(seqcE * 2)) );
    f16*   h0c  = (f16*)(ws + alloc((size_t)CHv * 64 * 1024 * 2));
    float* xp0  = (float*)(ws + alloc(2 * al(xpE * 4)));
    float* xp1  = (float*)(ws + alloc(2 * al(xpE * 4)));
    const size_t seqcStride = al(seqcE * 2) / sizeof(f16);
    const size_t xpStride   = al(xpE * 4) / sizeof(float);
    const int mtiles  = (CHv * 64) / 128;             // 32 or 16
    const int mtmask  = mtiles - 1;
    const int mtshift = (CHv == 64) ? 5 : 4;
    const int tpb     = (mtiles * 32) / 256;          // tiles per gemm block
    (void)in_sizes; (void)n_in; (void)out_size;

    fold_lora<<<1024, 256, 0, stream>>>(W_ih0, B_ih0, A_ih0, W0f, 512);
    fold_lora<<<2048, 256, 0, stream>>>(W_hh0, B_hh0, A_hh0, Wh0f, 1024);
    fold_lora<<<2048, 256, 0, stream>>>(W_ih1, B_ih1, A_ih1, W1f, 1024);
    fold_lora<<<2048, 256, 0, stream>>>(W_hh1, B_hh1, A_hh1, Wh1f, 1024);
    init_misc<<<256, 256, 0, stream>>>(b_ih0, b_hh0, b_ih1, b_hh1,
                                       bsum0, bsum1, flags0, flags1, c0st, c1st);

    // prologue: embed+gemm0 for chunk 0 (the only GEMM left on the timeline)
    embed_gather<<<CHv, 256, 0, stream>>>(x, emb, seqc, 0);
    gemm_nt<<<mtiles * 32, 256, 0, stream>>>(seqc, W0f, xp0, 512,
                                             mtmask, mtshift);
    for (int c = 0; c <= NCHv; c++) {
        if (c + 1 < NCHv)
            embed_gather<<<CHv, 256, 0, stream>>>(
                x, emb, seqc + ((c + 1) & 1) * seqcStride, (c + 1) * CHv);
        const bool g0 = (c + 1) < NCHv;   // gemm0(c+1) -> xp0[(c+1)&1]
        lstm_dual<<<768, 256, 0, stream>>>(
            xp0 + (c & 1) * xpStride, Wh0f, bsum0, (uint32_t*)h0c,
            flags0, c0st, (c < NCHv) ? c * CHv : -1, CHv - 1,
            xp1 + ((c + 1) & 1) * xpStride, Wh1f, bsum1, (uint32_t*)hx1,
            flags1, c1st, (c > 0) ? (c - 1) * CHv : -1,
            len, (float*)d_out, CHv,
            g0 ? (seqc + ((c + 1) & 1) * seqcStride) : nullptr, W0f, W1f,
            xp0 + ((c + 1) & 1) * xpStride,
            xp1 + (c & 1) * xpStride,
            tpb, mtmask, mtshift);
    }
}

// Round 8
// 7717.124 us; speedup vs baseline: 1.0808x; 1.0808x over previous
//
#include <hip/hip_runtime.h>
#include <stdint.h>

typedef _Float16 f16;
typedef _Float16 f16x8 __attribute__((ext_vector_type(8)));
typedef float f32x4 __attribute__((ext_vector_type(4)));

#define NBATCH 64

__device__ __forceinline__ float sigmoidf_(float x) {
    return 1.0f / (1.0f + __expf(-x));
}
__device__ __forceinline__ float tanh_(float x) {
    x = fminf(fmaxf(x, -15.0f), 15.0f);
    float e = __expf(2.0f * x);
    return (e - 1.0f) / (e + 1.0f);
}

// ---------------- fold LoRA into dense weight: dst = fp16(W + 2*B@A) --------
__global__ __launch_bounds__(256) void fold_lora(
    const float* __restrict__ W, const float* __restrict__ Bm,
    const float* __restrict__ Am, f16* __restrict__ dst, int K) {
    int cid = blockIdx.x * 256 + threadIdx.x;
    int kc = K >> 3;
    int r = cid / kc;
    int k0 = (cid - r * kc) * 8;
    float bb[8];
#pragma unroll
    for (int j = 0; j < 8; j++) bb[j] = Bm[r * 8 + j];
#pragma unroll
    for (int i = 0; i < 8; i++) {
        float s = 0.0f;
#pragma unroll
        for (int j = 0; j < 8; j++) s += bb[j] * Am[j * K + k0 + i];
        float v = W[(size_t)r * K + k0 + i] + 2.0f * s;
        dst[(size_t)r * K + k0 + i] = (f16)v;
    }
}

// ---------------- bias sums + flag/cstate zeroing ----------------------------
__global__ __launch_bounds__(256) void init_misc(
    const float* __restrict__ bih0, const float* __restrict__ bhh0,
    const float* __restrict__ bih1, const float* __restrict__ bhh1,
    float* __restrict__ bsum0, float* __restrict__ bsum1,
    int* __restrict__ flags0, int* __restrict__ flags1,
    float* __restrict__ c0, float* __restrict__ c1) {
    int i = blockIdx.x * 256 + threadIdx.x;
    if (i < 4096) {
        bsum0[i] = bih0[i] + bhh0[i];
        bsum1[i] = bih1[i] + bhh1[i];
    }
    if (i < 256) { flags0[i] = 0; flags1[i] = 0; }
    c0[i] = 0.0f;
    c1[i] = 0.0f;
}

// ---------------- embedding gather chunk -> fp16 seqc [CH][B][512] -----------
__global__ __launch_bounds__(256) void embed_gather(
    const int* __restrict__ x, const float* __restrict__ emb,
    f16* __restrict__ seqc, int t0) {
    int lt = blockIdx.x;
    int t = t0 + lt;
#pragma unroll
    for (int c = 0; c < 16; c++) {
        int lin = c * 256 + threadIdx.x;
        int b = lin >> 6;
        int e0 = (lin & 63) * 8;
        int tok = x[b * 512 + t];
        const float* src = emb + (size_t)tok * 512 + e0;
        f16x8 v;
#pragma unroll
        for (int i = 0; i < 8; i++) v[i] = (f16)src[i];
        *(f16x8*)&seqc[((size_t)lt * 64 + b) * 512 + e0] = v;
    }
}

// ---------------- 128x128 GEMM tile body (shared by standalone + in-dual) ----
// C = A[128 rows of M][K] @ Bw[128 rows of N][K]^T, gate-interleaved C write.
// ATOMIC_A: stage A via agent-scope uint64 loads (device-coherent; used for
// same-dispatch reads of h published by chain A with agent-scope stores).
template <bool ATOMIC_A>
__device__ __forceinline__ void gemm_tile(
    f16* As, f16* Bs, const f16* Aplain, const uint64_t* A64,
    const f16* __restrict__ Bw, float* __restrict__ C,
    int K, int mt, int nt) {
    int tid = threadIdx.x;
    int w = tid >> 6, lane = tid & 63;
    int lm = lane & 15, lq = lane >> 4;
    int wm = (w >> 1) * 64, wn = (w & 1) * 64;
    f32x4 acc[4][4];
#pragma unroll
    for (int i = 0; i < 4; i++)
#pragma unroll
        for (int j = 0; j < 4; j++) acc[i][j] = f32x4{0.f, 0.f, 0.f, 0.f};
    const f16* Ab = Aplain + (size_t)mt * 128 * K;
    const uint64_t* Ab64 = A64 + (size_t)mt * 128 * (K >> 2);
    const f16* Bb = Bw + (size_t)nt * 128 * K;
    int nkc = K >> 5;
    for (int kc = 0; kc < nkc; kc++) {
#pragma unroll
        for (int i = 0; i < 2; i++) {
            int cid = tid + i * 256;
            int r = cid >> 2, c8 = (cid & 3) * 8;
            if (ATOMIC_A) {
                size_t o = (size_t)r * (K >> 2) + (size_t)kc * 8 + (c8 >> 2);
                uint64_t v0 = __hip_atomic_load(Ab64 + o, __ATOMIC_RELAXED,
                                                __HIP_MEMORY_SCOPE_AGENT);
                uint64_t v1 = __hip_atomic_load(Ab64 + o + 1, __ATOMIC_RELAXED,
                                                __HIP_MEMORY_SCOPE_AGENT);
                *(uint64_t*)&As[r * 40 + c8] = v0;
                *(uint64_t*)&As[r * 40 + c8 + 4] = v1;
            } else {
                *(f16x8*)&As[r * 40 + c8] =
                    *(const f16x8*)&Ab[(size_t)r * K + kc * 32 + c8];
            }
            *(f16x8*)&Bs[r * 40 + c8] =
                *(const f16x8*)&Bb[(size_t)r * K + kc * 32 + c8];
        }
        __syncthreads();
        f16x8 af[4], bf[4];
#pragma unroll
        for (int mi = 0; mi < 4; mi++)
            af[mi] = *(const f16x8*)&As[(wm + mi * 16 + lm) * 40 + lq * 8];
#pragma unroll
        for (int ni = 0; ni < 4; ni++)
            bf[ni] = *(const f16x8*)&Bs[(wn + ni * 16 + lm) * 40 + lq * 8];
#pragma unroll
        for (int mi = 0; mi < 4; mi++)
#pragma unroll
            for (int ni = 0; ni < 4; ni++)
                acc[mi][ni] = __builtin_amdgcn_mfma_f32_16x16x32_f16(
                    af[mi], bf[ni], acc[mi][ni], 0, 0, 0);
        __syncthreads();
    }
#pragma unroll
    for (int mi = 0; mi < 4; mi++)
#pragma unroll
        for (int ni = 0; ni < 4; ni++)
#pragma unroll
            for (int r = 0; r < 4; r++) {
                int m = mt * 128 + wm + mi * 16 + lq * 4 + r;
                int n = nt * 128 + wn + ni * 16 + lm;
                int gate = n >> 10, u = n & 1023;
                C[(size_t)m * 4096 + u * 4 + gate] = acc[mi][ni][r];
            }
}

// ---------------- standalone NT GEMM (prologue chunk-0 xp only) --------------
__global__ __launch_bounds__(256) void gemm_nt(
    const f16* __restrict__ A, const f16* __restrict__ Bw,
    float* __restrict__ C, int K, int mtmask, int mtshift) {
    __shared__ __align__(16) char smem[20480];
    int bid = blockIdx.x;
    gemm_tile<false>((f16*)smem, (f16*)(smem + 10240), A, nullptr, Bw, C, K,
                     bid & mtmask, bid >> mtshift);
}

// ---------------- dual-chain persistent recurrence + streamed GEMMs ----------
// Blocks 0..255: layer-0 chunk c. Blocks 256..511: layer-1 chunk c-1.
// Blocks 512..767: gemm partition (gemm0(c+1), then gemm1(c) streaming behind
// chain A's flags). Round-7 regression diagnosis: (1) gemm poll loop hammered
// the flags0 MALL lines (~50ns period), (2) gemm waves stole issue slots from
// the latency-critical chains (all-block per-step barrier -> any slow CU sets
// the global period). Fixes: chain waves run at s_setprio(3) for the whole
// kernel (gemm waves stay prio 0 -> scheduler favors chains; T5 regime: wave
// role diversity), and gemm1's poll uses s_sleep(64) (~1.7us, 30x less flag
// traffic). Everything else identical to the functionally-verified round-7.

__device__ __forceinline__ void stage_h(f16* hbuf, const uint32_t* hx, int slot,
                                        int bg, int tid) {
    const uint64_t* hp = (const uint64_t*)hx + (size_t)slot * (NBATCH * 256);
#pragma unroll
    for (int i = 0; i < 16; i++) {
        int lin = tid + i * 256;          // [0,4096) 8B granules
        int b = lin >> 8, d = lin & 255;
        uint64_t v = __hip_atomic_load(hp + (size_t)(bg * 16 + b) * 256 + d,
                                       __ATOMIC_RELAXED, __HIP_MEMORY_SCOPE_AGENT);
        *(uint64_t*)((char*)hbuf + (size_t)b * 2064 + (size_t)d * 8) = v;
    }
}

__device__ __forceinline__ f32x4 recur_mfma(const f16* hb, const f16x8* wf) {
    f32x4 a0 = f32x4{0.f, 0.f, 0.f, 0.f};
    f32x4 a1 = f32x4{0.f, 0.f, 0.f, 0.f};
    f32x4 a2 = f32x4{0.f, 0.f, 0.f, 0.f};
    f32x4 a3 = f32x4{0.f, 0.f, 0.f, 0.f};
#pragma unroll
    for (int kk = 0; kk < 32; kk += 4) {
        a0 = __builtin_amdgcn_mfma_f32_16x16x32_f16(*(const f16x8*)(hb + (kk + 0) * 32), wf[kk + 0], a0, 0, 0, 0);
        a1 = __builtin_amdgcn_mfma_f32_16x16x32_f16(*(const f16x8*)(hb + (kk + 1) * 32), wf[kk + 1], a1, 0, 0, 0);
        a2 = __builtin_amdgcn_mfma_f32_16x16x32_f16(*(const f16x8*)(hb + (kk + 2) * 32), wf[kk + 2], a2, 0, 0, 0);
        a3 = __builtin_amdgcn_mfma_f32_16x16x32_f16(*(const f16x8*)(hb + (kk + 3) * 32), wf[kk + 3], a3, 0, 0, 0);
    }
    return (a0 + a1) + (a2 + a3);
}

// verified single-layer recurrence loop, parameterized by logical bid
__device__ __forceinline__ void chain_loop(
    const float* __restrict__ xp, const f16* __restrict__ Wh,
    const float* __restrict__ bsum, uint32_t* __restrict__ hexch,
    int* __restrict__ flags, float* __restrict__ cstate,
    int t0, int smask, const int* __restrict__ lengths,
    float* __restrict__ dout, int bid, int nsteps,
    f16* hbuf, float* xch) {
    int tid = threadIdx.x;
    int g = tid >> 6, lane = tid & 63;
    int lm = lane & 15, lq = lane >> 4;
    int bg = bid >> 6, jg = bid & 63;

    // W fragments resident in registers for all steps
    f16x8 wfrag[32];
    {
        int grow = g * 1024 + jg * 16 + lm;
        const f16* wp = Wh + (size_t)grow * 1024 + lq * 8;
#pragma unroll
        for (int kk = 0; kk < 32; kk++) wfrag[kk] = *(const f16x8*)(wp + kk * 32);
    }
    int eb = tid >> 4, eu = tid & 15;
    int batch = bg * 16 + eb;
    int hidx = jg * 16 + eu;
    float bias[4];
#pragma unroll
    for (int g2 = 0; g2 < 4; g2++) bias[g2] = bsum[g2 * 1024 + hidx];
    int mylen = (lengths != nullptr) ? lengths[batch] : -1;
    float c = (t0 > 0) ? cstate[(size_t)batch * 1024 + hidx] : 0.0f;
    const int myflag = bg * 64 + jg;

    for (int lt = 0; lt < nsteps; lt++) {
        int t = t0 + lt;
        // prefetch xp (recurrence-independent): latency hides under flag wait
        const f32x4 xpv = *(const f32x4*)(xp + ((size_t)lt * 64 + batch) * 4096 + (hidx << 2));
        f32x4 pre = f32x4{0.f, 0.f, 0.f, 0.f};
        if (t > 0) {
            if (tid < 64) {
                const int* fl = flags + bg * 64;
                for (;;) {
                    int v = __hip_atomic_load(fl + tid, __ATOMIC_RELAXED,
                                              __HIP_MEMORY_SCOPE_AGENT);
                    if (__all(v >= t)) break;
                    __builtin_amdgcn_s_sleep(1);
                }
            }
            __syncthreads();
            stage_h(hbuf, hexch, (t - 1) & smask, bg, tid);
            __syncthreads();
            pre = recur_mfma(&hbuf[lm * 1032 + lq * 8], wfrag);
        }
        // cross-wave exchange: D element (m=lq*4+r = batch-in-group, n=lm)
#pragma unroll
        for (int r = 0; r < 4; r++)
            xch[(g * 16 + lq * 4 + r) * 16 + lm] = pre[r];
        __syncthreads();
        float pg[4];
#pragma unroll
        for (int g2 = 0; g2 < 4; g2++)
            pg[g2] = xch[(g2 * 16 + eb) * 16 + eu] + xpv[g2] + bias[g2];
        float iv = sigmoidf_(pg[0]);
        float fv = sigmoidf_(pg[1]);
        float gv = tanh_(pg[2]);
        float ov = sigmoidf_(pg[3]);
        c = fv * c + iv * gv;
        float h = ov * tanh_(c);
        float hn = __shfl_xor(h, 1);
        if ((tid & 1) == 0) {
            uint16_t lo, hi;
            {
                f16 a = (f16)h, b2 = (f16)hn;
                lo = *(uint16_t*)&a; hi = *(uint16_t*)&b2;
            }
            uint32_t pk = (uint32_t)lo | ((uint32_t)hi << 16);
            __hip_atomic_store(
                hexch + (size_t)(t & smask) * (NBATCH * 512)
                      + (size_t)batch * 512 + (hidx >> 1),
                pk, __ATOMIC_RELAXED, __HIP_MEMORY_SCOPE_AGENT);
        }
        if (dout != nullptr && t == mylen - 1)
            dout[(size_t)batch * 1024 + hidx] = h;
        __syncthreads();  // drains vmcnt(0): all waves' h stores are at the MALL
        if (tid == 0)
            __hip_atomic_store(flags + myflag, t + 1, __ATOMIC_RELAXED,
                               __HIP_MEMORY_SCOPE_AGENT);
    }
    cstate[(size_t)batch * 1024 + hidx] = c;
}

__global__ __launch_bounds__(256, 3) void lstm_dual(
    const float* __restrict__ xpA, const f16* __restrict__ WhA,
    const float* __restrict__ bsA, uint32_t* __restrict__ hxA,
    int* __restrict__ flagsA, float* __restrict__ cstA, int t0a, int smaskA,
    const float* __restrict__ xpB, const f16* __restrict__ WhB,
    const float* __restrict__ bsB, uint32_t* __restrict__ hxB,
    int* __restrict__ flagsB, float* __restrict__ cstB, int t0b,
    const int* __restrict__ lengths, float* __restrict__ dout, int nsteps,
    const f16* __restrict__ seqcN, const f16* __restrict__ W0f,
    const f16* __restrict__ W1f, float* __restrict__ xp0out,
    float* __restrict__ xp1out, int tpb, int mtmaskG, int mtshiftG) {
    __shared__ __align__(16) char smem[37376];
    const int cid = blockIdx.x;
    if (cid < 256) {
        if (t0a < 0) return;           // uniform per block, before any barrier
        __builtin_amdgcn_s_setprio(3); // latency-critical: outrank gemm waves
        chain_loop(xpA, WhA, bsA, hxA, flagsA, cstA, t0a, smaskA,
                   nullptr, nullptr, cid, nsteps,
                   (f16*)smem, (float*)(smem + 33024));
    } else if (cid < 512) {
        if (t0b < 0) return;
        __builtin_amdgcn_s_setprio(3);
        chain_loop(xpB, WhB, bsB, hxB, flagsB, cstB, t0b, 1,
                   lengths, dout, cid - 256, nsteps,
                   (f16*)smem, (float*)(smem + 33024));
    } else {
        // throughput partition: stays at wave priority 0
        f16* As = (f16*)smem;
        f16* Bs = (f16*)(smem + 10240);
        const int gb = cid - 512;
        // gemm0(c+1): no intra-dispatch deps; fills the chains' idle shadow
        if (seqcN != nullptr) {
            for (int j = 0; j < tpb; j++) {
                int id = gb * tpb + j;
                gemm_tile<false>(As, Bs, seqcN, nullptr, W0f, xp0out, 512,
                                 id & mtmaskG, id >> mtshiftG);
            }
        }
        // gemm1(c): stream against chain A's flags (throttled poll: the tile
        // costs ~30us, so a ~1.7us sleep adds nothing but cuts MALL flag
        // traffic ~30x vs round-7's sleep(2))
        if (t0a >= 0) {
            for (int j = 0; j < tpb; j++) {
                int id = gb * tpb + j;
                int mt = id & mtmaskG, nt = id >> mtshiftG;
                int tneed = t0a + 2 * mt + 2;
                if (threadIdx.x < 64) {
                    int tx = threadIdx.x;
                    for (;;) {
                        int v0 = __hip_atomic_load(flagsA + tx, __ATOMIC_RELAXED,
                                                   __HIP_MEMORY_SCOPE_AGENT);
                        int v1 = __hip_atomic_load(flagsA + 64 + tx, __ATOMIC_RELAXED,
                                                   __HIP_MEMORY_SCOPE_AGENT);
                        int v2 = __hip_atomic_load(flagsA + 128 + tx, __ATOMIC_RELAXED,
                                                   __HIP_MEMORY_SCOPE_AGENT);
                        int v3 = __hip_atomic_load(flagsA + 192 + tx, __ATOMIC_RELAXED,
                                                   __HIP_MEMORY_SCOPE_AGENT);
                        int mn = min(min(v0, v1), min(v2, v3));
                        if (__all(mn >= tneed)) break;
                        __builtin_amdgcn_s_sleep(64);
                    }
                }
                __syncthreads();
                gemm_tile<true>(As, Bs, nullptr, (const uint64_t*)hxA, W1f,
                                xp1out, 1024, mt, nt);
            }
        }
    }
}

extern "C" void kernel_launch(void* const* d_in, const int* in_sizes, int n_in,
                              void* d_out, int out_size, void* d_ws, size_t ws_size,
                              hipStream_t stream) {
    const int*   x     = (const int*)d_in[0];
    const int*   len   = (const int*)d_in[1];
    const float* emb   = (const float*)d_in[2];
    const float* W_ih0 = (const float*)d_in[3];
    const float* b_ih0 = (const float*)d_in[4];
    const float* A_ih0 = (const float*)d_in[5];
    const float* B_ih0 = (const float*)d_in[6];
    const float* W_hh0 = (const float*)d_in[7];
    const float* b_hh0 = (const float*)d_in[8];
    const float* A_hh0 = (const float*)d_in[9];
    const float* B_hh0 = (const float*)d_in[10];
    const float* W_ih1 = (const float*)d_in[11];
    const float* b_ih1 = (const float*)d_in[12];
    const float* A_ih1 = (const float*)d_in[13];
    const float* B_ih1 = (const float*)d_in[14];
    const float* W_hh1 = (const float*)d_in[15];
    const float* b_hh1 = (const float*)d_in[16];
    const float* A_hh1 = (const float*)d_in[17];
    const float* B_hh1 = (const float*)d_in[18];

    char* ws = (char*)d_ws;
    size_t off = 0;
    auto alloc = [&](size_t bytes) {
        size_t o = off;
        off += (bytes + 255) & ~(size_t)255;
        return o;
    };
    f16*   W0f    = (f16*)(ws + alloc((size_t)4096 * 512 * 2));
    f16*   Wh0f   = (f16*)(ws + alloc((size_t)4096 * 1024 * 2));
    f16*   W1f    = (f16*)(ws + alloc((size_t)4096 * 1024 * 2));
    f16*   Wh1f   = (f16*)(ws + alloc((size_t)4096 * 1024 * 2));
    float* bsum0  = (float*)(ws + alloc(4096 * 4));
    float* bsum1  = (float*)(ws + alloc(4096 * 4));
    int*   flags0 = (int*)(ws + alloc(4096));
    int*   flags1 = (int*)(ws + alloc(4096));
    float* c0st   = (float*)(ws + alloc((size_t)64 * 1024 * 4));
    float* c1st   = (float*)(ws + alloc((size_t)64 * 1024 * 4));
    f16*   hx1    = (f16*)(ws + alloc((size_t)2 * 64 * 1024 * 2));

    // chunk length: prefer 64, fall back to 32 if double-buffered xp0/xp1 +
    // double seqc don't fit.
    auto al = [](size_t b) { return (b + 255) & ~(size_t)255; };
    auto need_for = [&](size_t CH) {
        return off + 2 * al(CH * 64 * 512 * 2)        // seqc x2
                   + al(CH * 64 * 1024 * 2)           // h0 ring
                   + 4 * al(CH * 64 * 4096 * 4);      // xp0 x2 + xp1 x2
    };
    int CHv = (ws_size >= need_for(64)) ? 64 : 32;
    const int NCHv = 512 / CHv;
    const size_t seqcE = (size_t)CHv * 64 * 512;      // f16 elems per buffer
    const size_t xpE   = (size_t)CHv * 64 * 4096;     // f32 elems per buffer
    f16*   seqc = (f16*)(ws + alloc(2 * al(seqcE * 2)) );
    f16*   h0c  = (f16*)(ws + alloc((size_t)CHv * 64 * 1024 * 2));
    float* xp0  = (float*)(ws + alloc(2 * al(xpE * 4)));
    float* xp1  = (float*)(ws + alloc(2 * al(xpE * 4)));
    const size_t seqcStride = al(seqcE * 2) / sizeof(f16);
    const size_t xpStride   = al(xpE * 4) / sizeof(float);
    const int mtiles  = (CHv * 64) / 128;             // 32 or 16
    const int mtmask  = mtiles - 1;
    const int mtshift = (CHv == 64) ? 5 : 4;
    const int tpb     = (mtiles * 32) / 256;          // tiles per gemm block
    (void)in_sizes; (void)n_in; (void)out_size;

    fold_lora<<<1024, 256, 0, stream>>>(W_ih0, B_ih0, A_ih0, W0f, 512);
    fold_lora<<<2048, 256, 0, stream>>>(W_hh0, B_hh0, A_hh0, Wh0f, 1024);
    fold_lora<<<2048, 256, 0, stream>>>(W_ih1, B_ih1, A_ih1, W1f, 1024);
    fold_lora<<<2048, 256, 0, stream>>>(W_hh1, B_hh1, A_hh1, Wh1f, 1024);
    init_misc<<<256, 256, 0, stream>>>(b_ih0, b_hh0, b_ih1, b_hh1,
                                       bsum0, bsum1, flags0, flags1, c0st, c1st);

    // prologue: embed+gemm0 for chunk 0 (the only GEMM left on the timeline)
    embed_gather<<<CHv, 256, 0, stream>>>(x, emb, seqc, 0);
    gemm_nt<<<mtiles * 32, 256, 0, stream>>>(seqc, W0f, xp0, 512,
                                             mtmask, mtshift);
    for (int c = 0; c <= NCHv; c++) {
        if (c + 1 < NCHv)
            embed_gather<<<CHv, 256, 0, stream>>>(
                x, emb, seqc + ((c + 1) & 1) * seqcStride, (c + 1) * CHv);
        const bool g0 = (c + 1) < NCHv;   // gemm0(c+1) -> xp0[(c+1)&1]
        lstm_dual<<<768, 256, 0, stream>>>(
            xp0 + (c & 1) * xpStride, Wh0f, bsum0, (uint32_t*)h0c,
            flags0, c0st, (c < NCHv) ? c * CHv : -1, CHv - 1,
            xp1 + ((c + 1) & 1) * xpStride, Wh1f, bsum1, (uint32_t*)hx1,
            flags1, c1st, (c > 0) ? (c - 1) * CHv : -1,
            len, (float*)d_out, CHv,
            g0 ? (seqc + ((c + 1) & 1) * seqcStride) : nullptr, W0f, W1f,
            xp0 + ((c + 1) & 1) * xpStride,
            xp1 + (c & 1) * xpStride,
            tpb, mtmask, mtshift);
    }
}

// Round 9
// 7052.512 us; speedup vs baseline: 1.1826x; 1.0942x over previous
//
#include <hip/hip_runtime.h>
#include <stdint.h>

typedef _Float16 f16;
typedef _Float16 f16x8 __attribute__((ext_vector_type(8)));
typedef float f32x4 __attribute__((ext_vector_type(4)));

#define NBATCH 64

__device__ __forceinline__ float sigmoidf_(float x) {
    return 1.0f / (1.0f + __expf(-x));
}
__device__ __forceinline__ float tanh_(float x) {
    x = fminf(fmaxf(x, -15.0f), 15.0f);
    float e = __expf(2.0f * x);
    return (e - 1.0f) / (e + 1.0f);
}

// ---------------- fold LoRA into dense weight: dst = fp16(W + 2*B@A) --------
__global__ __launch_bounds__(256) void fold_lora(
    const float* __restrict__ W, const float* __restrict__ Bm,
    const float* __restrict__ Am, f16* __restrict__ dst, int K) {
    int cid = blockIdx.x * 256 + threadIdx.x;
    int kc = K >> 3;
    int r = cid / kc;
    int k0 = (cid - r * kc) * 8;
    float bb[8];
#pragma unroll
    for (int j = 0; j < 8; j++) bb[j] = Bm[r * 8 + j];
#pragma unroll
    for (int i = 0; i < 8; i++) {
        float s = 0.0f;
#pragma unroll
        for (int j = 0; j < 8; j++) s += bb[j] * Am[j * K + k0 + i];
        float v = W[(size_t)r * K + k0 + i] + 2.0f * s;
        dst[(size_t)r * K + k0 + i] = (f16)v;
    }
}

// ---------------- bias sums + cstate zeroing ---------------------------------
__global__ __launch_bounds__(256) void init_misc(
    const float* __restrict__ bih0, const float* __restrict__ bhh0,
    const float* __restrict__ bih1, const float* __restrict__ bhh1,
    float* __restrict__ bsum0, float* __restrict__ bsum1,
    float* __restrict__ c0, float* __restrict__ c1) {
    int i = blockIdx.x * 256 + threadIdx.x;
    if (i < 4096) {
        bsum0[i] = bih0[i] + bhh0[i];
        bsum1[i] = bih1[i] + bhh1[i];
    }
    c0[i] = 0.0f;
    c1[i] = 0.0f;
}

// ---------------- sentinel-init tag words of an h-exchange buffer ------------
__global__ __launch_bounds__(256) void init_tags(uint64_t* __restrict__ p, int n) {
    int i = blockIdx.x * 256 + threadIdx.x;
    if (i < n) p[i] = 0xFFFFFFFF00000000ULL;
}

// ---------------- embedding gather chunk -> fp16 seqc [CH][B][512] -----------
__global__ __launch_bounds__(256) void embed_gather(
    const int* __restrict__ x, const float* __restrict__ emb,
    f16* __restrict__ seqc, int t0) {
    int lt = blockIdx.x;
    int t = t0 + lt;
#pragma unroll
    for (int c = 0; c < 16; c++) {
        int lin = c * 256 + threadIdx.x;
        int b = lin >> 6;
        int e0 = (lin & 63) * 8;
        int tok = x[b * 512 + t];
        const float* src = emb + (size_t)tok * 512 + e0;
        f16x8 v;
#pragma unroll
        for (int i = 0; i < 8; i++) v[i] = (f16)src[i];
        *(f16x8*)&seqc[((size_t)lt * 64 + b) * 512 + e0] = v;
    }
}

// ---------------- 128x128 GEMM tile body -------------------------------------
// AMODE 0: plain f16 A.  AMODE 1: tagged-u64 A (h-pair in low 32, tag in high
// 32; K>>1 granules per row) -- cross-dispatch read of the tagged h-exchange.
template <int AMODE>
__device__ __forceinline__ void gemm_tile(
    f16* As, f16* Bs, const f16* Aplain, const uint64_t* A64,
    const f16* __restrict__ Bw, float* __restrict__ C,
    int K, int mt, int nt) {
    int tid = threadIdx.x;
    int w = tid >> 6, lane = tid & 63;
    int lm = lane & 15, lq = lane >> 4;
    int wm = (w >> 1) * 64, wn = (w & 1) * 64;
    f32x4 acc[4][4];
#pragma unroll
    for (int i = 0; i < 4; i++)
#pragma unroll
        for (int j = 0; j < 4; j++) acc[i][j] = f32x4{0.f, 0.f, 0.f, 0.f};
    const f16* Ab = Aplain + (size_t)mt * 128 * K;
    const uint64_t* Ab64 = A64 + (size_t)mt * 128 * (K >> 1);
    const f16* Bb = Bw + (size_t)nt * 128 * K;
    int nkc = K >> 5;
    for (int kc = 0; kc < nkc; kc++) {
#pragma unroll
        for (int i = 0; i < 2; i++) {
            int cid = tid + i * 256;
            int r = cid >> 2, c8 = (cid & 3) * 8;
            if (AMODE == 1) {
                size_t o = (size_t)r * (K >> 1) + (size_t)kc * 16 + (c8 >> 1);
                uint64_t q0 = Ab64[o],     q1 = Ab64[o + 1];
                uint64_t q2 = Ab64[o + 2], q3 = Ab64[o + 3];
                uint32_t* dst = (uint32_t*)&As[r * 40 + c8];
                dst[0] = (uint32_t)q0; dst[1] = (uint32_t)q1;
                dst[2] = (uint32_t)q2; dst[3] = (uint32_t)q3;
            } else {
                *(f16x8*)&As[r * 40 + c8] =
                    *(const f16x8*)&Ab[(size_t)r * K + kc * 32 + c8];
            }
            *(f16x8*)&Bs[r * 40 + c8] =
                *(const f16x8*)&Bb[(size_t)r * K + kc * 32 + c8];
        }
        __syncthreads();
        f16x8 af[4], bf[4];
#pragma unroll
        for (int mi = 0; mi < 4; mi++)
            af[mi] = *(const f16x8*)&As[(wm + mi * 16 + lm) * 40 + lq * 8];
#pragma unroll
        for (int ni = 0; ni < 4; ni++)
            bf[ni] = *(const f16x8*)&Bs[(wn + ni * 16 + lm) * 40 + lq * 8];
#pragma unroll
        for (int mi = 0; mi < 4; mi++)
#pragma unroll
            for (int ni = 0; ni < 4; ni++)
                acc[mi][ni] = __builtin_amdgcn_mfma_f32_16x16x32_f16(
                    af[mi], bf[ni], acc[mi][ni], 0, 0, 0);
        __syncthreads();
    }
#pragma unroll
    for (int mi = 0; mi < 4; mi++)
#pragma unroll
        for (int ni = 0; ni < 4; ni++)
#pragma unroll
            for (int r = 0; r < 4; r++) {
                int m = mt * 128 + wm + mi * 16 + lq * 4 + r;
                int n = nt * 128 + wn + ni * 16 + lm;
                int gate = n >> 10, u = n & 1023;
                C[(size_t)m * 4096 + u * 4 + gate] = acc[mi][ni][r];
            }
}

// ---------------- merged per-chunk GEMM dispatch -----------------------------
// Partitions (disjoint buffers, no cross-partition deps):
//   [0,G)    gemm0(c):  seqc[c&1] @ W0f -> xp0          (if A0 != null)
//   [G,2G)   gemm1(c):  tagged h0c @ W1f -> xp1         (if A1 != null)
//   [2G,2G+CH) embed(c+1) -> seqc[(c+1)&1]              (if seqcN != null)
// Runs BETWEEN duals (stream order) -- bulk traffic never co-resident with
// the latency-critical chains (round-7/8 lesson: MALL queuing poisons them).
__global__ __launch_bounds__(256) void gemm_combo(
    const f16* __restrict__ A0, const f16* __restrict__ W0f,
    float* __restrict__ xp0,
    const uint64_t* __restrict__ A1, const f16* __restrict__ W1f,
    float* __restrict__ xp1,
    const int* __restrict__ x, const float* __restrict__ emb,
    f16* __restrict__ seqcN, int t0N,
    int G, int mtmask, int mtshift) {
    __shared__ __align__(16) char smem[20480];
    int bid = blockIdx.x;
    if (bid < G) {
        if (A0 == nullptr) return;
        gemm_tile<0>((f16*)smem, (f16*)(smem + 10240), A0, nullptr, W0f, xp0,
                     512, bid & mtmask, bid >> mtshift);
    } else if (bid < 2 * G) {
        if (A1 == nullptr) return;
        int id = bid - G;
        gemm_tile<1>((f16*)smem, (f16*)(smem + 10240), nullptr, A1, W1f, xp1,
                     1024, id & mtmask, id >> mtshift);
    } else {
        if (seqcN == nullptr) return;
        int lt = bid - 2 * G;
        int t = t0N + lt;
#pragma unroll
        for (int c = 0; c < 16; c++) {
            int lin = c * 256 + threadIdx.x;
            int b = lin >> 6;
            int e0 = (lin & 63) * 8;
            int tok = x[b * 512 + t];
            const float* src = emb + (size_t)tok * 512 + e0;
            f16x8 v;
#pragma unroll
            for (int i = 0; i < 8; i++) v[i] = (f16)src[i];
            *(f16x8*)&seqcN[((size_t)lt * 64 + b) * 512 + e0] = v;
        }
    }
}

// ---------------- dual-chain persistent recurrence (tagged exchange) ---------
// Round-6 structure (blocks 0..255 layer-0 chunk c, 256..511 layer-1 chunk
// c-1, disjoint CUs) with the flag mechanism replaced by DATA-AS-FLAG: each
// published granule is a u64 {tag=t (hi32), f16-pair (lo32)} relaxed agent
// store. Consumers stage 32 granules (pipelined 2x16 register batches), check
// tags, retry stragglers. Removes flag-store + flag-propagate + poll (one
// MALL propagation instead of 2+). Ring safety: observing tag T from block S
// implies S's whole block passed its stage-of-(T-1) barrier (publish is
// post-barrier), so overwriting the slot holding T-2 is safe -> depth-2 ring
// suffices (chain B); chain A's ring is depth-CH (whole chunk, read by gemm1
// next dispatch). Tags absolute t; sentinel 0xFFFFFFFF init per launch.

__device__ __forceinline__ f32x4 recur_mfma(const f16* hb, const f16x8* wf) {
    f32x4 a0 = f32x4{0.f, 0.f, 0.f, 0.f};
    f32x4 a1 = f32x4{0.f, 0.f, 0.f, 0.f};
    f32x4 a2 = f32x4{0.f, 0.f, 0.f, 0.f};
    f32x4 a3 = f32x4{0.f, 0.f, 0.f, 0.f};
#pragma unroll
    for (int kk = 0; kk < 32; kk += 4) {
        a0 = __builtin_amdgcn_mfma_f32_16x16x32_f16(*(const f16x8*)(hb + (kk + 0) * 32), wf[kk + 0], a0, 0, 0, 0);
        a1 = __builtin_amdgcn_mfma_f32_16x16x32_f16(*(const f16x8*)(hb + (kk + 1) * 32), wf[kk + 1], a1, 0, 0, 0);
        a2 = __builtin_amdgcn_mfma_f32_16x16x32_f16(*(const f16x8*)(hb + (kk + 2) * 32), wf[kk + 2], a2, 0, 0, 0);
        a3 = __builtin_amdgcn_mfma_f32_16x16x32_f16(*(const f16x8*)(hb + (kk + 3) * 32), wf[kk + 3], a3, 0, 0, 0);
    }
    return (a0 + a1) + (a2 + a3);
}

__device__ __forceinline__ void chain_loop(
    const float* __restrict__ xp, const f16* __restrict__ Wh,
    const float* __restrict__ bsum, uint64_t* __restrict__ hexch,
    float* __restrict__ cstate, int t0, int smask,
    const int* __restrict__ lengths, float* __restrict__ dout,
    int bid, int nsteps, f16* hbuf, float* xch) {
    int tid = threadIdx.x;
    int g = tid >> 6, lane = tid & 63;
    int lm = lane & 15, lq = lane >> 4;
    int bg = bid >> 6, jg = bid & 63;

    // W fragments resident in registers for all steps
    f16x8 wfrag[32];
    {
        int grow = g * 1024 + jg * 16 + lm;
        const f16* wp = Wh + (size_t)grow * 1024 + lq * 8;
#pragma unroll
        for (int kk = 0; kk < 32; kk++) wfrag[kk] = *(const f16x8*)(wp + kk * 32);
    }
    int eb = tid >> 4, eu = tid & 15;
    int batch = bg * 16 + eb;
    int hidx = jg * 16 + eu;
    float bias[4];
#pragma unroll
    for (int g2 = 0; g2 < 4; g2++) bias[g2] = bsum[g2 * 1024 + hidx];
    int mylen = (lengths != nullptr) ? lengths[batch] : -1;
    float c = (t0 > 0) ? cstate[(size_t)batch * 1024 + hidx] : 0.0f;

    for (int lt = 0; lt < nsteps; lt++) {
        int t = t0 + lt;
        // prefetch xp (recurrence-independent): latency hides under stage
        const f32x4 xpv = *(const f32x4*)(xp + ((size_t)lt * 64 + batch) * 4096 + (hidx << 2));
        f32x4 pre = f32x4{0.f, 0.f, 0.f, 0.f};
        if (t > 0) {
            // tagged stage: no flags, no poll. 8192 granules/block, 32/thread.
            const uint64_t* hp = hexch
                + (size_t)((t - 1) & smask) * (NBATCH * 512)
                + (size_t)bg * 16 * 512;
            const uint32_t etag = (uint32_t)(t - 1);
#pragma unroll
            for (int half = 0; half < 2; half++) {
                uint64_t v[16];
#pragma unroll
                for (int i = 0; i < 16; i++) {
                    int lin = tid + (half * 16 + i) * 256;
                    v[i] = __hip_atomic_load(
                        hp + (size_t)(lin >> 9) * 512 + (lin & 511),
                        __ATOMIC_RELAXED, __HIP_MEMORY_SCOPE_AGENT);
                }
#pragma unroll
                for (int i = 0; i < 16; i++) {
                    int lin = tid + (half * 16 + i) * 256;
                    while ((uint32_t)(v[i] >> 32) != etag) {
                        __builtin_amdgcn_s_sleep(1);
                        v[i] = __hip_atomic_load(
                            hp + (size_t)(lin >> 9) * 512 + (lin & 511),
                            __ATOMIC_RELAXED, __HIP_MEMORY_SCOPE_AGENT);
                    }
                }
#pragma unroll
                for (int i = 0; i < 16; i++) {
                    int lin = tid + (half * 16 + i) * 256;
                    int b = lin >> 9, d = lin & 511;
                    *(uint32_t*)((char*)hbuf + (size_t)b * 2064 + (size_t)d * 4)
                        = (uint32_t)v[i];
                }
            }
            __syncthreads();
            pre = recur_mfma(&hbuf[lm * 1032 + lq * 8], wfrag);
        }
        // cross-wave exchange: D element (m=lq*4+r = batch-in-group, n=lm)
#pragma unroll
        for (int r = 0; r < 4; r++)
            xch[(g * 16 + lq * 4 + r) * 16 + lm] = pre[r];
        __syncthreads();
        float pg[4];
#pragma unroll
        for (int g2 = 0; g2 < 4; g2++)
            pg[g2] = xch[(g2 * 16 + eb) * 16 + eu] + xpv[g2] + bias[g2];
        float iv = sigmoidf_(pg[0]);
        float fv = sigmoidf_(pg[1]);
        float gv = tanh_(pg[2]);
        float ov = sigmoidf_(pg[3]);
        c = fv * c + iv * gv;
        float h = ov * tanh_(c);
        // publish h: one tagged u64 per f16 pair; visible as soon as it lands
        float hn = __shfl_xor(h, 1);
        if ((tid & 1) == 0) {
            uint16_t lo, hi;
            {
                f16 a = (f16)h, b2 = (f16)hn;
                lo = *(uint16_t*)&a; hi = *(uint16_t*)&b2;
            }
            uint32_t pk = (uint32_t)lo | ((uint32_t)hi << 16);
            uint64_t q = ((uint64_t)(uint32_t)t << 32) | (uint64_t)pk;
            __hip_atomic_store(
                hexch + (size_t)(t & smask) * (NBATCH * 512)
                      + (size_t)batch * 512 + (hidx >> 1),
                q, __ATOMIC_RELAXED, __HIP_MEMORY_SCOPE_AGENT);
        }
        if (dout != nullptr && t == mylen - 1)
            dout[(size_t)batch * 1024 + hidx] = h;
        __syncthreads();  // hbuf/xch reuse guard; drains publishes toward MALL
    }
    cstate[(size_t)batch * 1024 + hidx] = c;
}

__global__ __launch_bounds__(256, 2) void lstm_dual(
    const float* __restrict__ xpA, const f16* __restrict__ WhA,
    const float* __restrict__ bsA, uint64_t* __restrict__ hxA,
    float* __restrict__ cstA, int t0a, int smaskA,
    const float* __restrict__ xpB, const f16* __restrict__ WhB,
    const float* __restrict__ bsB, uint64_t* __restrict__ hxB,
    float* __restrict__ cstB, int t0b,
    const int* __restrict__ lengths, float* __restrict__ dout, int nsteps) {
    __shared__ f16 hbuf[16 * 1032];
    __shared__ float xch[4 * 16 * 16];
    const int cid = blockIdx.x;
    if (cid < 256) {
        if (t0a < 0) return;           // uniform per block, before any barrier
        chain_loop(xpA, WhA, bsA, hxA, cstA, t0a, smaskA,
                   nullptr, nullptr, cid, nsteps, hbuf, xch);
    } else {
        if (t0b < 0) return;
        chain_loop(xpB, WhB, bsB, hxB, cstB, t0b, 1,
                   lengths, dout, cid - 256, nsteps, hbuf, xch);
    }
}

extern "C" void kernel_launch(void* const* d_in, const int* in_sizes, int n_in,
                              void* d_out, int out_size, void* d_ws, size_t ws_size,
                              hipStream_t stream) {
    const int*   x     = (const int*)d_in[0];
    const int*   len   = (const int*)d_in[1];
    const float* emb   = (const float*)d_in[2];
    const float* W_ih0 = (const float*)d_in[3];
    const float* b_ih0 = (const float*)d_in[4];
    const float* A_ih0 = (const float*)d_in[5];
    const float* B_ih0 = (const float*)d_in[6];
    const float* W_hh0 = (const float*)d_in[7];
    const float* b_hh0 = (const float*)d_in[8];
    const float* A_hh0 = (const float*)d_in[9];
    const float* B_hh0 = (const float*)d_in[10];
    const float* W_ih1 = (const float*)d_in[11];
    const float* b_ih1 = (const float*)d_in[12];
    const float* A_ih1 = (const float*)d_in[13];
    const float* B_ih1 = (const float*)d_in[14];
    const float* W_hh1 = (const float*)d_in[15];
    const float* b_hh1 = (const float*)d_in[16];
    const float* A_hh1 = (const float*)d_in[17];
    const float* B_hh1 = (const float*)d_in[18];

    char* ws = (char*)d_ws;
    size_t off = 0;
    auto alloc = [&](size_t bytes) {
        size_t o = off;
        off += (bytes + 255) & ~(size_t)255;
        return o;
    };
    f16*   W0f    = (f16*)(ws + alloc((size_t)4096 * 512 * 2));
    f16*   Wh0f   = (f16*)(ws + alloc((size_t)4096 * 1024 * 2));
    f16*   W1f    = (f16*)(ws + alloc((size_t)4096 * 1024 * 2));
    f16*   Wh1f   = (f16*)(ws + alloc((size_t)4096 * 1024 * 2));
    float* bsum0  = (float*)(ws + alloc(4096 * 4));
    float* bsum1  = (float*)(ws + alloc(4096 * 4));
    float* c0st   = (float*)(ws + alloc((size_t)64 * 1024 * 4));
    float* c1st   = (float*)(ws + alloc((size_t)64 * 1024 * 4));
    uint64_t* hx1 = (uint64_t*)(ws + alloc((size_t)2 * 64 * 512 * 8));

    // chunk length: prefer 64; fall back to 32 if buffers don't fit.
    auto al = [](size_t b) { return (b + 255) & ~(size_t)255; };
    auto need_for = [&](size_t CH) {
        return off + 2 * al(CH * 64 * 512 * 2)        // seqc x2
                   + al(CH * 64 * 512 * 8)            // tagged h0c ring
                   + 2 * al(CH * 64 * 4096 * 4);      // xp0, xp1
    };
    int CHv = (ws_size >= need_for(64)) ? 64 : 32;
    const int NCHv = 512 / CHv;
    const size_t seqcE = (size_t)CHv * 64 * 512;
    f16*      seqc = (f16*)(ws + alloc(2 * al(seqcE * 2)));
    uint64_t* h0c  = (uint64_t*)(ws + alloc((size_t)CHv * 64 * 512 * 8));
    float*    xp0  = (float*)(ws + alloc((size_t)CHv * 64 * 4096 * 4));
    float*    xp1  = (float*)(ws + alloc((size_t)CHv * 64 * 4096 * 4));
    const size_t seqcStride = al(seqcE * 2) / sizeof(f16);
    const int mtiles  = (CHv * 64) / 128;             // 32 or 16
    const int mtmask  = mtiles - 1;
    const int mtshift = (CHv == 64) ? 5 : 4;
    const int G       = mtiles * 32;                  // gemm blocks per op
    (void)in_sizes; (void)n_in; (void)out_size;

    fold_lora<<<1024, 256, 0, stream>>>(W_ih0, B_ih0, A_ih0, W0f, 512);
    fold_lora<<<2048, 256, 0, stream>>>(W_hh0, B_hh0, A_hh0, Wh0f, 1024);
    fold_lora<<<2048, 256, 0, stream>>>(W_ih1, B_ih1, A_ih1, W1f, 1024);
    fold_lora<<<2048, 256, 0, stream>>>(W_hh1, B_hh1, A_hh1, Wh1f, 1024);
    init_misc<<<256, 256, 0, stream>>>(b_ih0, b_hh0, b_ih1, b_hh1,
                                       bsum0, bsum1, c0st, c1st);
    {
        int n0 = CHv * 64 * 512;                      // h0c granules
        init_tags<<<(n0 + 255) / 256, 256, 0, stream>>>(h0c, n0);
        init_tags<<<(2 * 64 * 512 + 255) / 256, 256, 0, stream>>>(hx1,
                                                                  2 * 64 * 512);
    }

    // prologue: embed chunk 0; then per c: combo(c) {gemm0(c), gemm1(c),
    // embed(c+1)} followed by dual(c) {layer-0 chunk c, layer-1 chunk c-1}.
    embed_gather<<<CHv, 256, 0, stream>>>(x, emb, seqc, 0);
    for (int c = 0; c <= NCHv; c++) {
        const f16* A0 = (c < NCHv) ? seqc + (c & 1) * seqcStride : nullptr;
        const uint64_t* A1 = (c > 0) ? h0c : nullptr;
        f16* sN = (c + 1 < NCHv) ? seqc + ((c + 1) & 1) * seqcStride : nullptr;
        gemm_combo<<<2 * G + CHv, 256, 0, stream>>>(
            A0, W0f, xp0, A1, W1f, xp1, x, emb, sN, (c + 1) * CHv,
            G, mtmask, mtshift);
        lstm_dual<<<512, 256, 0, stream>>>(
            xp0, Wh0f, bsum0, h0c, c0st,
            (c < NCHv) ? c * CHv : -1, CHv - 1,
            xp1, Wh1f, bsum1, hx1, c1st,
            (c > 0) ? (c - 1) * CHv : -1,
            len, (float*)d_out, CHv);
    }
}